// Round 5
// baseline (1283.136 us; speedup 1.0000x reference)
//
#include <hip/hip_runtime.h>

typedef unsigned short u16;
using short8_t  = __attribute__((ext_vector_type(8)))  short;
using float16_t = __attribute__((ext_vector_type(16))) float;

#define NKT 260          // K-steps of 16: K = 64*64 + 64 = 4160
#define DEG_CAP 32

__device__ __forceinline__ float bf2f(u16 b) { return __uint_as_float(((unsigned)b) << 16); }
__device__ __forceinline__ u16 f2bf(float f) {
  unsigned u = __float_as_uint(f);
  return (u16)((u + 0x7fffu + ((u >> 16) & 1u)) >> 16);   // RNE
}

union U8 { short8_t s; uint4 v; unsigned u[4]; };

// z = (h * x) rounded to bf16 (round-half-up), 8 elems; v_perm merges hi/lo halves.
// hs == 1.0f reproduces x exactly (low 16 bits zero -> +0x8000 doesn't carry).
__device__ __forceinline__ short8_t scale8(short8_t x8, float hs) {
  U8 in, out;
  in.s = x8;
  #pragma unroll
  for (int p = 0; p < 4; ++p) {
    unsigned w = in.u[p];
    float lo = __uint_as_float(w << 16) * hs;
    float hi = __uint_as_float(w & 0xffff0000u) * hs;
    unsigned lor = __float_as_uint(lo) + 0x8000u;
    unsigned hir = __float_as_uint(hi) + 0x8000u;
    out.u[p] = __builtin_amdgcn_perm(hir, lor, 0x07060302);  // [hir.hi16 | lor.hi16]
  }
  return out.s;
}

// ---------------- relu(X @ W + b): f32 in, bf16 out. W is [IN,64] f32 ----------------
template<int IN>
__global__ __launch_bounds__(256) void affine_relu_kernel(
    const float* __restrict__ Xin, const float* __restrict__ W, const float* __restrict__ Bv,
    u16* __restrict__ Xout, int N)
{
  int gid = blockIdx.x * 256 + threadIdx.x;
  int n = gid >> 6, o = gid & 63;
  if (n >= N) return;
  float acc = Bv[o];
  #pragma unroll
  for (int i = 0; i < IN; ++i)
    acc = fmaf(Xin[n * IN + i], W[i * 64 + o], acc);
  Xout[gid] = f2bf(fmaxf(acc, 0.f));
}

// ---------------- pack B_ext [4160,64] (f32 w2/b2) into bf16 MFMA per-lane fragment order ----
__global__ __launch_bounds__(256) void bpack_kernel(
    const float* __restrict__ w2, const float* __restrict__ b2, u16* __restrict__ Bp)
{
  int gid = blockIdx.x * 256 + threadIdx.x;
  if (gid >= NKT * 128) return;
  int lane = gid & 63;
  int nt = (gid >> 6) & 1;
  int kt = gid >> 7;
  int o = nt * 32 + (lane & 31);
  int kbase = kt * 16 + (lane >> 5) * 8;
  u16 vals[8];
  #pragma unroll
  for (int j = 0; j < 8; ++j) {
    int k = kbase + j;
    vals[j] = f2bf((k < 4096) ? w2[(k >> 6) * 4096 + (k & 63) * 64 + o]
                              : b2[(k - 4096) * 64 + o]);
  }
  uint4 pack;
  pack.x = (unsigned)vals[0] | ((unsigned)vals[1] << 16);
  pack.y = (unsigned)vals[2] | ((unsigned)vals[3] << 16);
  pack.z = (unsigned)vals[4] | ((unsigned)vals[5] << 16);
  pack.w = (unsigned)vals[6] | ((unsigned)vals[7] << 16);
  *(uint4*)(Bp + (size_t)gid * 8) = pack;
}

// ---------------- bucketed CSR: one pass, no scan ----------------
__global__ __launch_bounds__(256) void hist_kernel(
    const int* __restrict__ eidx, int* __restrict__ cnt, int* __restrict__ elist, int E)
{
  int e = blockIdx.x * 256 + threadIdx.x;
  if (e < E) {
    int tg = eidx[E + e];
    int pos = atomicAdd(cnt + tg, 1);
    if (pos < DEG_CAP) elist[(size_t)tg * DEG_CAP + pos] = e;
  }
}

// ---------------- msg = [h (x) x, x] @ B_ext ----------------
// grid ceil(E/64), block 256 = 4 waves. Block stages 64 edges; wave wid handles
// K-quarter kt in [wid*65, wid*65+65) over ALL 64 rows (2 row tiles x 2 col tiles).
// Quarter accumulators reduced in-block via LDS atomicAdd -> single msg write.
__global__ __launch_bounds__(256) void msg_gemm_kernel(
    const u16* __restrict__ X, const u16* __restrict__ Hh,
    const u16* __restrict__ Bp, const int* __restrict__ eidx,
    float* __restrict__ msg, int E)
{
  // x laid out [chunk 0..7][row 0..63][8 u16]: ds_read_b128 conflict-free per tile
  __shared__ __align__(16) u16 x_lds[8 * 64 * 8];     // 8 KB
  __shared__ __align__(16) u16 h_lds[64 * 72];        // 9 KB, stride-72 rows
  __shared__ __align__(16) float acc_lds[64 * 64];    // 16 KB
  const int t = threadIdx.x;
  const int e0 = blockIdx.x * 64;
  const int rows = E - e0;

  { // zero acc tile
    float4 z4 = make_float4(0.f, 0.f, 0.f, 0.f);
    #pragma unroll
    for (int c = 0; c < 4; ++c) ((float4*)acc_lds)[t + c * 256] = z4;
    // stage h: 512 uint4, coalesced
    const uint4* hsrc = (const uint4*)(Hh + (size_t)e0 * 64);
    #pragma unroll
    for (int c = 0; c < 2; ++c) {
      int idx = t + c * 256;               // 0..511
      int row = idx >> 3;
      uint4 val = make_uint4(0, 0, 0, 0);
      if (row < rows) val = hsrc[idx];
      *(uint4*)(h_lds + row * 72 + (idx & 7) * 8) = val;
    }
    // stage x: gather by src, 4 threads/row, 32 B each -> 2 chunk slots
    int r = t >> 2, part = t & 3;
    uint4 v0 = make_uint4(0, 0, 0, 0), v1 = v0;
    if (r < rows) {
      int s = eidx[e0 + r];
      const uint4* xp = (const uint4*)(X + (size_t)s * 64);
      v0 = xp[part * 2]; v1 = xp[part * 2 + 1];
    }
    *(uint4*)(x_lds + ((part * 2 + 0) * 64 + r) * 8) = v0;
    *(uint4*)(x_lds + ((part * 2 + 1) * 64 + r) * 8) = v1;
  }
  __syncthreads();

  const int lane = t & 63;
  const int wid = t >> 6;
  const int ml = lane & 31;
  const int q  = lane >> 5;
  const int r0 = ml;
  const int r1 = 32 + ml;
  const u16* hrow0 = h_lds + r0 * 72;
  const u16* hrow1 = h_lds + r1 * 72;

  float16_t acc00, acc01, acc10, acc11;
  #pragma unroll
  for (int i = 0; i < 16; ++i) { acc00[i] = 0.f; acc01[i] = 0.f; acc10[i] = 0.f; acc11[i] = 0.f; }

  const uint4* bbase = (const uint4*)Bp + lane;
  const int ktA = wid * 65;
  const int ktB = ktA + 65;

  U8 b0, b1;
  b0.v = bbase[(ktA * 2 + 0) * 64];
  b1.v = bbase[(ktA * 2 + 1) * 64];
  for (int kt = ktA; kt < ktB; ++kt) {
    U8 nb0 = b0, nb1 = b1;
    if (kt + 1 < ktB) {                       // prefetch next B fragments
      nb0.v = bbase[((kt + 1) * 2 + 0) * 64];
      nb1.v = bbase[((kt + 1) * 2 + 1) * 64];
    }
    int xoff = (((kt & 3) * 2 + q) * 64) * 8;
    short8_t x80 = *(const short8_t*)(x_lds + xoff + r0 * 8);
    short8_t x81 = *(const short8_t*)(x_lds + xoff + r1 * 8);
    float hs0 = (kt < 256) ? bf2f(hrow0[kt >> 2]) : 1.0f;   // tail rows: A = x
    float hs1 = (kt < 256) ? bf2f(hrow1[kt >> 2]) : 1.0f;
    short8_t a0 = scale8(x80, hs0);
    short8_t a1 = scale8(x81, hs1);
    acc00 = __builtin_amdgcn_mfma_f32_32x32x16_bf16(a0, b0.s, acc00, 0, 0, 0);
    acc01 = __builtin_amdgcn_mfma_f32_32x32x16_bf16(a0, b1.s, acc01, 0, 0, 0);
    acc10 = __builtin_amdgcn_mfma_f32_32x32x16_bf16(a1, b0.s, acc10, 0, 0, 0);
    acc11 = __builtin_amdgcn_mfma_f32_32x32x16_bf16(a1, b1.s, acc11, 0, 0, 0);
    b0 = nb0; b1 = nb1;
  }

  // cross-wave K-reduce into LDS tile. C/D layout: col=lane&31, row=(reg&3)+8*(reg>>2)+4*q
  #pragma unroll
  for (int reg = 0; reg < 16; ++reg) {
    int row = (reg & 3) + 8 * (reg >> 2) + 4 * q;
    atomicAdd(acc_lds + row * 64 + ml,             acc00[reg]);
    atomicAdd(acc_lds + row * 64 + 32 + ml,        acc01[reg]);
    atomicAdd(acc_lds + (32 + row) * 64 + ml,      acc10[reg]);
    atomicAdd(acc_lds + (32 + row) * 64 + 32 + ml, acc11[reg]);
  }
  __syncthreads();

  // coalesced write-out: 1024 uint4
  #pragma unroll
  for (int c = 0; c < 4; ++c) {
    int idx = t + c * 256;                 // uint4 index; row = idx>>4
    int row = idx >> 4;
    if (row < rows)
      ((uint4*)msg)[(size_t)(e0 + row) * 16 + (idx & 15)] = ((const uint4*)acc_lds)[idx];
  }
}

// ---------------- x_new = relu(x @ root + gather_mean(msg) + bias) ----------------
// 16 nodes/block, 4 waves; wave ln handles nodes n0+ln*4+{0..3}; o = lane
__global__ __launch_bounds__(256) void update_kernel(
    const u16* __restrict__ Xin, const float* __restrict__ msg,
    const int* __restrict__ cnt, const int* __restrict__ elist,
    const float* __restrict__ root, const float* __restrict__ bias,
    u16* __restrict__ Xout, int N)
{
  __shared__ float root_s[64 * 64];
  int t = threadIdx.x;
  for (int idx = t; idx < 4096; idx += 256) root_s[idx] = root[idx];
  __syncthreads();
  int o = t & 63, ln = t >> 6;
  int n0 = blockIdx.x * 16 + ln * 4;
  for (int s = 0; s < 4; ++s) {
    int n = n0 + s;
    if (n >= N) break;                       // wave-uniform
    int c = cnt[n];
    int cc = c < DEG_CAP ? c : DEG_CAP;
    float agg = 0.f;
    for (int j = 0; j < cc; ++j) {
      int e = elist[(size_t)n * DEG_CAP + j];
      agg += msg[(size_t)e * 64 + o];
    }
    if (c > 1) agg *= 1.0f / (float)c;
    float xv = bf2f(Xin[(size_t)n * 64 + o]);
    float acc = bias[o] + agg;
    #pragma unroll
    for (int i = 0; i < 64; ++i)
      acc = fmaf(__shfl(xv, i, 64), root_s[i * 64 + o], acc);
    Xout[(size_t)n * 64 + o] = f2bf(fmaxf(acc, 0.f));
  }
}

// ---------------- column-sum pool: vectorized grid-stride ----------------
// nchunks = N*8 uint4-chunks; grid stride 256*256 (multiple of 8 -> fixed col group)
__global__ __launch_bounds__(256) void pool_kernel(const u16* __restrict__ X, float* __restrict__ out64, int nchunks)
{
  __shared__ float red[64];
  int t = threadIdx.x;
  if (t < 64) red[t] = 0.f;
  __syncthreads();
  int gid = blockIdx.x * 256 + t;
  float s[8];
  #pragma unroll
  for (int j = 0; j < 8; ++j) s[j] = 0.f;
  for (int i = gid; i < nchunks; i += 256 * 256) {
    uint4 v = ((const uint4*)X)[i];
    s[0] += bf2f((u16)(v.x & 0xffffu)); s[1] += bf2f((u16)(v.x >> 16));
    s[2] += bf2f((u16)(v.y & 0xffffu)); s[3] += bf2f((u16)(v.y >> 16));
    s[4] += bf2f((u16)(v.z & 0xffffu)); s[5] += bf2f((u16)(v.z >> 16));
    s[6] += bf2f((u16)(v.w & 0xffffu)); s[7] += bf2f((u16)(v.w >> 16));
  }
  int cg = (gid & 7) * 8;
  #pragma unroll
  for (int j = 0; j < 8; ++j) atomicAdd(red + cg + j, s[j]);
  __syncthreads();
  if (t < 64) atomicAdd(out64 + t, red[t]);
}

// ---------------- head: parallel per-layer GEMV ----------------
__global__ __launch_bounds__(256) void prep_head_kernel(
    const float* __restrict__ pg, const float* __restrict__ plg, const float* __restrict__ adduct,
    float* __restrict__ v)
{
  int t = threadIdx.x;
  if (t < 131) v[t] = (t < 64) ? pg[t] : (t < 128 ? plg[t - 64] : adduct[t - 128]);
}

__global__ __launch_bounds__(256) void gemv_relu_kernel(
    const float* __restrict__ in, const float* __restrict__ W, const float* __restrict__ b,
    float* __restrict__ out, int Ni, int No)
{
  __shared__ float red[16][17];
  int t = threadIdx.x;
  int ol = t & 15, ig = t >> 4;
  int o = blockIdx.x * 16 + ol;
  float s = 0.f;
  for (int i = ig; i < Ni; i += 16)
    s = fmaf(in[i], W[i * No + o], s);
  red[ig][ol] = s;
  __syncthreads();
  if (t < 16) {
    int oo = blockIdx.x * 16 + t;
    float acc = b[oo];
    #pragma unroll
    for (int g = 0; g < 16; ++g) acc += red[g][t];
    out[oo] = fmaxf(acc, 0.f);
  }
}

__global__ __launch_bounds__(384) void final_kernel(
    const float* __restrict__ u, const float* __restrict__ l2w, const float* __restrict__ l2b,
    float* __restrict__ out)
{
  __shared__ float wred[6];
  int t = threadIdx.x;
  float p = u[t] * l2w[t];
  #pragma unroll
  for (int off = 32; off > 0; off >>= 1) p += __shfl_down(p, off);
  if ((t & 63) == 0) wred[t >> 6] = p;
  __syncthreads();
  if (t == 0) {
    float s = l2b[0];
    #pragma unroll
    for (int i = 0; i < 6; ++i) s += wred[i];
    out[0] = s;
  }
}

// ---------------- host driver ----------------
template<int INX, int INE>
static void run_branch(const float* Xraw, const float* l0w, const float* l0b,
                       const int* eidx, const float* ea,
                       const float* w1, const float* b1, const float* w2, const float* b2,
                       const float* root, const float* bias,
                       int N, int E,
                       u16* xa, u16* xb, u16* hbuf, u16* bp,
                       float* msg, int* cnt, int* elist, float* pool,
                       hipStream_t stream)
{
  affine_relu_kernel<INX><<<(N * 64 + 255) / 256, 256, 0, stream>>>(Xraw, l0w, l0b, xa, N);
  affine_relu_kernel<INE><<<(E * 64 + 255) / 256, 256, 0, stream>>>(ea, w1, b1, hbuf, E);
  bpack_kernel<<<(NKT * 128 + 255) / 256, 256, 0, stream>>>(w2, b2, bp);
  hipMemsetAsync(cnt, 0, (size_t)N * 4, stream);
  hist_kernel<<<(E + 255) / 256, 256, 0, stream>>>(eidx, cnt, elist, E);
  u16* xc = xa; u16* xn = xb;
  for (int it = 0; it < 3; ++it) {
    msg_gemm_kernel<<<(E + 63) / 64, 256, 0, stream>>>(xc, hbuf, bp, eidx, msg, E);
    update_kernel<<<(N + 15) / 16, 256, 0, stream>>>(xc, msg, cnt, elist, root, bias, xn, N);
    u16* tmp = xc; xc = xn; xn = tmp;
  }
  hipMemsetAsync(pool, 0, 64 * 4, stream);
  pool_kernel<<<256, 256, 0, stream>>>(xc, pool, N * 8);
}

extern "C" void kernel_launch(void* const* d_in, const int* in_sizes, int n_in,
                              void* d_out, int out_size, void* d_ws, size_t ws_size,
                              hipStream_t stream)
{
  const int NG = 30000, EG = 60000, NLG = 60000, ELG = 60000;

  const float* gx      = (const float*)d_in[0];
  const int*   g_ei    = (const int*)  d_in[1];
  const float* g_ea    = (const float*)d_in[2];
  const float* lgx     = (const float*)d_in[3];
  const int*   lg_ei   = (const int*)  d_in[4];
  const float* lg_ea   = (const float*)d_in[5];
  const float* adduct  = (const float*)d_in[6];
  const float* lin0_w  = (const float*)d_in[7];
  const float* lin0_b  = (const float*)d_in[8];
  const float* g_w1    = (const float*)d_in[9];
  const float* g_b1    = (const float*)d_in[10];
  const float* g_w2    = (const float*)d_in[11];
  const float* g_b2    = (const float*)d_in[12];
  const float* g_root  = (const float*)d_in[13];
  const float* g_bias  = (const float*)d_in[14];
  const float* l0lg_w  = (const float*)d_in[15];
  const float* l0lg_b  = (const float*)d_in[16];
  const float* lg_w1   = (const float*)d_in[17];
  const float* lg_b1   = (const float*)d_in[18];
  const float* lg_w2   = (const float*)d_in[19];
  const float* lg_b2   = (const float*)d_in[20];
  const float* lg_root = (const float*)d_in[21];
  const float* lg_bias = (const float*)d_in[22];
  const float* bott_w  = (const float*)d_in[23];
  const float* bott_b  = (const float*)d_in[24];
  const float* lin1_w  = (const float*)d_in[25];
  const float* lin1_b  = (const float*)d_in[26];
  const float* lin2_w  = (const float*)d_in[27];
  const float* lin2_b  = (const float*)d_in[28];

  char* p = (char*)d_ws;
  auto alloc = [&](size_t bytes) { char* r = p; p += (bytes + 255) & ~(size_t)255; return r; };
  // shared between the two sequential branches (~47 MB total)
  u16*   xa     = (u16*)  alloc((size_t)NLG * 64 * 2);
  u16*   xb     = (u16*)  alloc((size_t)NLG * 64 * 2);
  u16*   hbuf   = (u16*)  alloc((size_t)ELG * 64 * 2);
  u16*   bp     = (u16*)  alloc((size_t)NKT * 128 * 8 * 2);
  float* msg    = (float*)alloc((size_t)ELG * 64 * 4);
  int*   cnt    = (int*)  alloc((size_t)NLG * 4);
  int*   elist  = (int*)  alloc((size_t)NLG * DEG_CAP * 4);
  float* pool_g = (float*)alloc(64 * 4);
  float* pool_l = (float*)alloc(64 * 4);
  float* hv     = (float*)alloc(131 * 4);
  float* h0     = (float*)alloc(384 * 4);
  float* h1     = (float*)alloc(384 * 4);

  run_branch<20, 4>(gx, lin0_w, lin0_b, g_ei, g_ea, g_w1, g_b1, g_w2, g_b2, g_root, g_bias,
                    NG, EG, xa, xb, hbuf, bp, msg, cnt, elist, pool_g, stream);
  run_branch<5, 1>(lgx, l0lg_w, l0lg_b, lg_ei, lg_ea, lg_w1, lg_b1, lg_w2, lg_b2, lg_root, lg_bias,
                   NLG, ELG, xa, xb, hbuf, bp, msg, cnt, elist, pool_l, stream);

  prep_head_kernel<<<1, 256, 0, stream>>>(pool_g, pool_l, adduct, hv);
  gemv_relu_kernel<<<24, 256, 0, stream>>>(hv, bott_w, bott_b, h0, 131, 384);
  float* ua = h0; float* ub = h1;
  for (int L = 0; L < 6; ++L) {
    gemv_relu_kernel<<<24, 256, 0, stream>>>(ua, lin1_w, lin1_b, ub, 384, 384);
    float* tmp = ua; ua = ub; ub = tmp;
  }
  final_kernel<<<1, 384, 0, stream>>>(ua, lin2_w, lin2_b, (float*)d_out);
}

// Round 8
// 1026.769 us; speedup vs baseline: 1.2497x; 1.2497x over previous
//
#include <hip/hip_runtime.h>

typedef unsigned short u16;
using short8_t  = __attribute__((ext_vector_type(8)))  short;
using float16_t = __attribute__((ext_vector_type(16))) float;

#define NKT 260          // K-steps of 16: K = 64*64 + 64 = 4160
#define DEG_CAP 32
#define NCHUNK 32        // full 8-kt chunks; chunk 32 = 4-kt tail (8 frags)

__device__ __forceinline__ float bf2f(u16 b) { return __uint_as_float(((unsigned)b) << 16); }
__device__ __forceinline__ u16 f2bf(float f) {
  unsigned u = __float_as_uint(f);
  return (u16)((u + 0x7fffu + ((u >> 16) & 1u)) >> 16);   // RNE
}

union U8 { short8_t s; uint4 v; unsigned u[4]; };

// z = (h * x) rounded to bf16 (round-half-up), 8 elems — matches R4-passing version
__device__ __forceinline__ short8_t scale8(short8_t x8, float hs) {
  U8 in, out;
  in.s = x8;
  #pragma unroll
  for (int p = 0; p < 4; ++p) {
    unsigned w = in.u[p];
    float lo = __uint_as_float(w << 16) * hs;
    float hi = __uint_as_float(w & 0xffff0000u) * hs;
    unsigned lor = __float_as_uint(lo) + 0x8000u;
    unsigned hir = __float_as_uint(hi) + 0x8000u;
    out.u[p] = __builtin_amdgcn_perm(hir, lor, 0x07060302);  // [hir.hi16 | lor.hi16]
  }
  return out.s;
}

// ---------------- relu(X @ W + b): f32 in, bf16 out. W is [IN,64] f32 ----------------
template<int IN>
__global__ __launch_bounds__(256) void affine_relu_kernel(
    const float* __restrict__ Xin, const float* __restrict__ W, const float* __restrict__ Bv,
    u16* __restrict__ Xout, int N)
{
  int gid = blockIdx.x * 256 + threadIdx.x;
  int n = gid >> 6, o = gid & 63;
  if (n >= N) return;
  float acc = Bv[o];
  #pragma unroll
  for (int i = 0; i < IN; ++i)
    acc = fmaf(Xin[n * IN + i], W[i * 64 + o], acc);
  Xout[gid] = f2bf(fmaxf(acc, 0.f));
}

// ---------------- pack B_ext [4160,64] (f32 w2/b2) into bf16 MFMA per-lane fragment order ----
__global__ __launch_bounds__(256) void bpack_kernel(
    const float* __restrict__ w2, const float* __restrict__ b2, u16* __restrict__ Bp)
{
  int gid = blockIdx.x * 256 + threadIdx.x;
  if (gid >= NKT * 128) return;
  int lane = gid & 63;
  int nt = (gid >> 6) & 1;
  int kt = gid >> 7;
  int o = nt * 32 + (lane & 31);
  int kbase = kt * 16 + (lane >> 5) * 8;
  u16 vals[8];
  #pragma unroll
  for (int j = 0; j < 8; ++j) {
    int k = kbase + j;
    vals[j] = f2bf((k < 4096) ? w2[(k >> 6) * 4096 + (k & 63) * 64 + o]
                              : b2[(k - 4096) * 64 + o]);
  }
  uint4 pack;
  pack.x = (unsigned)vals[0] | ((unsigned)vals[1] << 16);
  pack.y = (unsigned)vals[2] | ((unsigned)vals[3] << 16);
  pack.z = (unsigned)vals[4] | ((unsigned)vals[5] << 16);
  pack.w = (unsigned)vals[6] | ((unsigned)vals[7] << 16);
  *(uint4*)(Bp + (size_t)gid * 8) = pack;
}

// ---------------- bucketed CSR: one pass, no scan ----------------
__global__ __launch_bounds__(256) void hist_kernel(
    const int* __restrict__ eidx, int* __restrict__ cnt, int* __restrict__ elist, int E)
{
  int e = blockIdx.x * 256 + threadIdx.x;
  if (e < E) {
    int tg = eidx[E + e];
    int pos = atomicAdd(cnt + tg, 1);
    if (pos < DEG_CAP) elist[(size_t)tg * DEG_CAP + pos] = e;
  }
}

// ---------------- msg = [h (x) x, x] @ B_ext ----------------
// block = 256 thr (4 waves) = 128 edges; wave wid owns rows [wid*32, wid*32+32),
// full K, all 64 cols. B double-buffered through LDS in 8-kt (16 KB) chunks:
// per chunk each thread global-loads 4 uint4 into regs and ds_writes them,
// pipelined two chunks ahead. x slices in registers; h in LDS.
__global__ __launch_bounds__(256, 2) void msg_gemm_kernel(
    const u16* __restrict__ X, const u16* __restrict__ Hh,
    const u16* __restrict__ Bp, const int* __restrict__ eidx,
    float* __restrict__ msg, int E)
{
  __shared__ __align__(16) u16 b_lds[2][16 * 512];   // 32 KB double buffer
  __shared__ __align__(16) u16 h_lds[128 * 72];      // 18 KB, stride-72 rows
  const int t = threadIdx.x;
  const int lane = t & 63;
  const int wid = t >> 6;
  const int ml = lane & 31;
  const int q = lane >> 5;
  const int e0 = blockIdx.x * 128;

  const uint4* bpv = (const uint4*)Bp;    // 1024 uint4 per chunk

  // prologue: chunk0 -> regs -> buf0; chunk1 -> regs (written at c=0)
  uint4 st[4];
  #pragma unroll
  for (int i = 0; i < 4; ++i) st[i] = bpv[t + i * 256];
  { // stage h: 128 rows x 8 uint4 = 1024 uint4 (R6/R7 bug: only staged 64 rows)
    const uint4* hsrc = (const uint4*)(Hh + (size_t)e0 * 64);
    int rows = E - e0;
    #pragma unroll
    for (int c2 = 0; c2 < 4; ++c2) {
      int idx = t + c2 * 256;
      int row = idx >> 3;
      if (row < rows)
        *(uint4*)(h_lds + row * 72 + (idx & 7) * 8) = hsrc[idx];
    }
  }
  #pragma unroll
  for (int i = 0; i < 4; ++i)
    *(uint4*)(&b_lds[0][(t + i * 256) * 8]) = st[i];
  #pragma unroll
  for (int i = 0; i < 4; ++i) st[i] = bpv[1024 + t + i * 256];

  // x in registers: lane (ml,q) holds slices s=0..3 = elems [s*16+q*8, +8) of its row
  U8 xr[4];
  {
    int e = e0 + wid * 32 + ml;
    int src = (e < E) ? eidx[e] : 0;
    const u16* xp = X + (size_t)src * 64 + q * 8;
    xr[0].v = *(const uint4*)(xp);
    xr[1].v = *(const uint4*)(xp + 16);
    xr[2].v = *(const uint4*)(xp + 32);
    xr[3].v = *(const uint4*)(xp + 48);
  }
  __syncthreads();

  float16_t acc0, acc1;
  #pragma unroll
  for (int i = 0; i < 16; ++i) { acc0[i] = 0.f; acc1[i] = 0.f; }

  const u16* hr = h_lds + (wid * 32 + ml) * 72;

  for (int c = 0; c < NCHUNK; ++c) {
    // ds_write chunk c+1 (regs loaded at c-1 / prologue) into the other buffer;
    // its previous readers (iter c-1) all passed the barrier at end of c-1.
    u16* wbuf = b_lds[(c + 1) & 1];
    #pragma unroll
    for (int i = 0; i < 4; ++i)
      *(uint4*)(wbuf + (t + i * 256) * 8) = st[i];
    if (c < NCHUNK - 1) {                  // load chunk c+2 (chunk 32 = padded tail)
      #pragma unroll
      for (int i = 0; i < 4; ++i)
        st[i] = bpv[(size_t)(c + 2) * 1024 + t + i * 256];
    }
    // compute chunk c
    const u16* bb = b_lds[c & 1];
    #pragma unroll
    for (int g = 0; g < 2; ++g) {
      float hs = bf2f(hr[c * 2 + g]);          // h[row][kq], kq = c*2+g
      #pragma unroll
      for (int s = 0; s < 4; ++s) {
        int fl = (g * 4 + s) * 2;
        short8_t a = scale8(xr[s].s, hs);
        U8 b0, b1;
        b0.v = *(const uint4*)(bb + (fl << 9) + lane * 8);
        b1.v = *(const uint4*)(bb + ((fl + 1) << 9) + lane * 8);
        acc0 = __builtin_amdgcn_mfma_f32_32x32x16_bf16(a, b0.s, acc0, 0, 0, 0);
        acc1 = __builtin_amdgcn_mfma_f32_32x32x16_bf16(a, b1.s, acc1, 0, 0, 0);
      }
    }
    __syncthreads();
  }
  { // tail: kt 256..259 (b2 rows), A = x unscaled; frags 0..7 of chunk 32 now in buf0
    const u16* bb = b_lds[NCHUNK & 1];
    #pragma unroll
    for (int s = 0; s < 4; ++s) {
      int fl = s * 2;
      U8 b0, b1;
      b0.v = *(const uint4*)(bb + (fl << 9) + lane * 8);
      b1.v = *(const uint4*)(bb + ((fl + 1) << 9) + lane * 8);
      acc0 = __builtin_amdgcn_mfma_f32_32x32x16_bf16(xr[s].s, b0.s, acc0, 0, 0, 0);
      acc1 = __builtin_amdgcn_mfma_f32_32x32x16_bf16(xr[s].s, b1.s, acc1, 0, 0, 0);
    }
  }

  // epilogue: C/D layout col=lane&31, row=(reg&3)+8*(reg>>2)+4*q
  #pragma unroll
  for (int reg = 0; reg < 16; ++reg) {
    int row = (reg & 3) + 8 * (reg >> 2) + 4 * q;
    int e = e0 + wid * 32 + row;
    if (e < E) {
      msg[(size_t)e * 64 + ml]      = acc0[reg];
      msg[(size_t)e * 64 + 32 + ml] = acc1[reg];
    }
  }
}

// ---------------- x_new = relu(x @ root + gather_mean(msg) + bias) ----------------
__global__ __launch_bounds__(256) void update_kernel(
    const u16* __restrict__ Xin, const float* __restrict__ msg,
    const int* __restrict__ cnt, const int* __restrict__ elist,
    const float* __restrict__ root, const float* __restrict__ bias,
    u16* __restrict__ Xout, int N)
{
  __shared__ float root_s[64 * 64];
  int t = threadIdx.x;
  for (int idx = t; idx < 4096; idx += 256) root_s[idx] = root[idx];
  __syncthreads();
  int o = t & 63, ln = t >> 6;
  int n0 = blockIdx.x * 16 + ln * 4;
  for (int s = 0; s < 4; ++s) {
    int n = n0 + s;
    if (n >= N) break;                       // wave-uniform
    int c = cnt[n];
    int cc = c < DEG_CAP ? c : DEG_CAP;
    float agg = 0.f;
    for (int j = 0; j < cc; ++j) {
      int e = elist[(size_t)n * DEG_CAP + j];
      agg += msg[(size_t)e * 64 + o];
    }
    if (c > 1) agg *= 1.0f / (float)c;
    float xv = bf2f(Xin[(size_t)n * 64 + o]);
    float acc = bias[o] + agg;
    #pragma unroll
    for (int i = 0; i < 64; ++i)
      acc = fmaf(__shfl(xv, i, 64), root_s[i * 64 + o], acc);
    Xout[(size_t)n * 64 + o] = f2bf(fmaxf(acc, 0.f));
  }
}

// ---------------- column-sum pool: vectorized grid-stride ----------------
__global__ __launch_bounds__(256) void pool_kernel(const u16* __restrict__ X, float* __restrict__ out64, int nchunks)
{
  __shared__ float red[64];
  int t = threadIdx.x;
  if (t < 64) red[t] = 0.f;
  __syncthreads();
  int gid = blockIdx.x * 256 + t;
  float s[8];
  #pragma unroll
  for (int j = 0; j < 8; ++j) s[j] = 0.f;
  for (int i = gid; i < nchunks; i += 256 * 256) {
    uint4 v = ((const uint4*)X)[i];
    s[0] += bf2f((u16)(v.x & 0xffffu)); s[1] += bf2f((u16)(v.x >> 16));
    s[2] += bf2f((u16)(v.y & 0xffffu)); s[3] += bf2f((u16)(v.y >> 16));
    s[4] += bf2f((u16)(v.z & 0xffffu)); s[5] += bf2f((u16)(v.z >> 16));
    s[6] += bf2f((u16)(v.w & 0xffffu)); s[7] += bf2f((u16)(v.w >> 16));
  }
  int cg = (gid & 7) * 8;
  #pragma unroll
  for (int j = 0; j < 8; ++j) atomicAdd(red + cg + j, s[j]);
  __syncthreads();
  if (t < 64) atomicAdd(out64 + t, red[t]);
}

// ---------------- head: parallel per-layer GEMV ----------------
__global__ __launch_bounds__(256) void prep_head_kernel(
    const float* __restrict__ pg, const float* __restrict__ plg, const float* __restrict__ adduct,
    float* __restrict__ v)
{
  int t = threadIdx.x;
  if (t < 131) v[t] = (t < 64) ? pg[t] : (t < 128 ? plg[t - 64] : adduct[t - 128]);
}

__global__ __launch_bounds__(256) void gemv_relu_kernel(
    const float* __restrict__ in, const float* __restrict__ W, const float* __restrict__ b,
    float* __restrict__ out, int Ni, int No)
{
  __shared__ float red[16][17];
  int t = threadIdx.x;
  int ol = t & 15, ig = t >> 4;
  int o = blockIdx.x * 16 + ol;
  float s = 0.f;
  for (int i = ig; i < Ni; i += 16)
    s = fmaf(in[i], W[i * No + o], s);
  red[ig][ol] = s;
  __syncthreads();
  if (t < 16) {
    int oo = blockIdx.x * 16 + t;
    float acc = b[oo];
    #pragma unroll
    for (int g = 0; g < 16; ++g) acc += red[g][t];
    out[oo] = fmaxf(acc, 0.f);
  }
}

__global__ __launch_bounds__(384) void final_kernel(
    const float* __restrict__ u, const float* __restrict__ l2w, const float* __restrict__ l2b,
    float* __restrict__ out)
{
  __shared__ float wred[6];
  int t = threadIdx.x;
  float p = u[t] * l2w[t];
  #pragma unroll
  for (int off = 32; off > 0; off >>= 1) p += __shfl_down(p, off);
  if ((t & 63) == 0) wred[t >> 6] = p;
  __syncthreads();
  if (t == 0) {
    float s = l2b[0];
    #pragma unroll
    for (int i = 0; i < 6; ++i) s += wred[i];
    out[0] = s;
  }
}

// ---------------- host driver ----------------
template<int INX, int INE>
static void run_branch(const float* Xraw, const float* l0w, const float* l0b,
                       const int* eidx, const float* ea,
                       const float* w1, const float* b1, const float* w2, const float* b2,
                       const float* root, const float* bias,
                       int N, int E,
                       u16* xa, u16* xb, u16* hbuf, u16* bp,
                       float* msg, int* cnt, int* elist, float* pool,
                       hipStream_t stream)
{
  affine_relu_kernel<INX><<<(N * 64 + 255) / 256, 256, 0, stream>>>(Xraw, l0w, l0b, xa, N);
  affine_relu_kernel<INE><<<(E * 64 + 255) / 256, 256, 0, stream>>>(ea, w1, b1, hbuf, E);
  bpack_kernel<<<(NKT * 128 + 255) / 256, 256, 0, stream>>>(w2, b2, bp);
  hipMemsetAsync(cnt, 0, (size_t)N * 4, stream);
  hist_kernel<<<(E + 255) / 256, 256, 0, stream>>>(eidx, cnt, elist, E);
  u16* xc = xa; u16* xn = xb;
  for (int it = 0; it < 3; ++it) {
    msg_gemm_kernel<<<(E + 127) / 128, 256, 0, stream>>>(xc, hbuf, bp, eidx, msg, E);
    update_kernel<<<(N + 15) / 16, 256, 0, stream>>>(xc, msg, cnt, elist, root, bias, xn, N);
    u16* tmp = xc; xc = xn; xn = tmp;
  }
  hipMemsetAsync(pool, 0, 64 * 4, stream);
  pool_kernel<<<256, 256, 0, stream>>>(xc, pool, N * 8);
}

extern "C" void kernel_launch(void* const* d_in, const int* in_sizes, int n_in,
                              void* d_out, int out_size, void* d_ws, size_t ws_size,
                              hipStream_t stream)
{
  const int NG = 30000, EG = 60000, NLG = 60000, ELG = 60000;

  const float* gx      = (const float*)d_in[0];
  const int*   g_ei    = (const int*)  d_in[1];
  const float* g_ea    = (const float*)d_in[2];
  const float* lgx     = (const float*)d_in[3];
  const int*   lg_ei   = (const int*)  d_in[4];
  const float* lg_ea   = (const float*)d_in[5];
  const float* adduct  = (const float*)d_in[6];
  const float* lin0_w  = (const float*)d_in[7];
  const float* lin0_b  = (const float*)d_in[8];
  const float* g_w1    = (const float*)d_in[9];
  const float* g_b1    = (const float*)d_in[10];
  const float* g_w2    = (const float*)d_in[11];
  const float* g_b2    = (const float*)d_in[12];
  const float* g_root  = (const float*)d_in[13];
  const float* g_bias  = (const float*)d_in[14];
  const float* l0lg_w  = (const float*)d_in[15];
  const float* l0lg_b  = (const float*)d_in[16];
  const float* lg_w1   = (const float*)d_in[17];
  const float* lg_b1   = (const float*)d_in[18];
  const float* lg_w2   = (const float*)d_in[19];
  const float* lg_b2   = (const float*)d_in[20];
  const float* lg_root = (const float*)d_in[21];
  const float* lg_bias = (const float*)d_in[22];
  const float* bott_w  = (const float*)d_in[23];
  const float* bott_b  = (const float*)d_in[24];
  const float* lin1_w  = (const float*)d_in[25];
  const float* lin1_b  = (const float*)d_in[26];
  const float* lin2_w  = (const float*)d_in[27];
  const float* lin2_b  = (const float*)d_in[28];

  char* p = (char*)d_ws;
  auto alloc = [&](size_t bytes) { char* r = p; p += (bytes + 255) & ~(size_t)255; return r; };
  // shared between the two sequential branches (~47 MB total)
  u16*   xa     = (u16*)  alloc((size_t)NLG * 64 * 2);
  u16*   xb     = (u16*)  alloc((size_t)NLG * 64 * 2);
  u16*   hbuf   = (u16*)  alloc((size_t)ELG * 64 * 2);
  u16*   bp     = (u16*)  alloc((size_t)33 * 16 * 1024);   // 33 chunks (tail padded)
  float* msg    = (float*)alloc((size_t)ELG * 64 * 4);
  int*   cnt    = (int*)  alloc((size_t)NLG * 4);
  int*   elist  = (int*)  alloc((size_t)NLG * DEG_CAP * 4);
  float* pool_g = (float*)alloc(64 * 4);
  float* pool_l = (float*)alloc(64 * 4);
  float* hv     = (float*)alloc(131 * 4);
  float* h0     = (float*)alloc(384 * 4);
  float* h1     = (float*)alloc(384 * 4);

  run_branch<20, 4>(gx, lin0_w, lin0_b, g_ei, g_ea, g_w1, g_b1, g_w2, g_b2, g_root, g_bias,
                    NG, EG, xa, xb, hbuf, bp, msg, cnt, elist, pool_g, stream);
  run_branch<5, 1>(lgx, l0lg_w, l0lg_b, lg_ei, lg_ea, lg_w1, lg_b1, lg_w2, lg_b2, lg_root, lg_bias,
                   NLG, ELG, xa, xb, hbuf, bp, msg, cnt, elist, pool_l, stream);

  prep_head_kernel<<<1, 256, 0, stream>>>(pool_g, pool_l, adduct, hv);
  gemv_relu_kernel<<<24, 256, 0, stream>>>(hv, bott_w, bott_b, h0, 131, 384);
  float* ua = h0; float* ub = h1;
  for (int L = 0; L < 6; ++L) {
    gemv_relu_kernel<<<24, 256, 0, stream>>>(ua, lin1_w, lin1_b, ub, 384, 384);
    float* tmp = ua; ua = ub; ub = tmp;
  }
  final_kernel<<<1, 384, 0, stream>>>(ua, lin2_w, lin2_b, (float*)d_out);
}

// Round 9
// 947.353 us; speedup vs baseline: 1.3544x; 1.0838x over previous
//
#include <hip/hip_runtime.h>

typedef unsigned short u16;
using short8_t  = __attribute__((ext_vector_type(8)))  short;
using float16_t = __attribute__((ext_vector_type(16))) float;

#define NKT 260          // K-steps of 16: K = 64*64 + 64 = 4160
#define DEG_CAP 32

__device__ __forceinline__ float bf2f(u16 b) { return __uint_as_float(((unsigned)b) << 16); }
__device__ __forceinline__ u16 f2bf(float f) {
  unsigned u = __float_as_uint(f);
  return (u16)((u + 0x7fffu + ((u >> 16) & 1u)) >> 16);   // RNE
}

union U8 { short8_t s; uint4 v; unsigned u[4]; };

// z = (h * x) rounded to bf16 (round-half-up), 8 elems; hs==1.0 reproduces x exactly
__device__ __forceinline__ short8_t scale8(short8_t x8, float hs) {
  U8 in, out;
  in.s = x8;
  #pragma unroll
  for (int p = 0; p < 4; ++p) {
    unsigned w = in.u[p];
    float lo = __uint_as_float(w << 16) * hs;
    float hi = __uint_as_float(w & 0xffff0000u) * hs;
    unsigned lor = __float_as_uint(lo) + 0x8000u;
    unsigned hir = __float_as_uint(hi) + 0x8000u;
    out.u[p] = __builtin_amdgcn_perm(hir, lor, 0x07060302);  // [hir.hi16 | lor.hi16]
  }
  return out.s;
}

// ---------------- relu(X @ W + b): f32 in, bf16 out. W is [IN,64] f32 ----------------
template<int IN>
__global__ __launch_bounds__(256) void affine_relu_kernel(
    const float* __restrict__ Xin, const float* __restrict__ W, const float* __restrict__ Bv,
    u16* __restrict__ Xout, int N)
{
  int gid = blockIdx.x * 256 + threadIdx.x;
  int n = gid >> 6, o = gid & 63;
  if (n >= N) return;
  float acc = Bv[o];
  #pragma unroll
  for (int i = 0; i < IN; ++i)
    acc = fmaf(Xin[n * IN + i], W[i * 64 + o], acc);
  Xout[gid] = f2bf(fmaxf(acc, 0.f));
}

// ---------------- pack B_ext [4160,64] (f32 w2/b2) into bf16 MFMA per-lane fragment order ----
__global__ __launch_bounds__(256) void bpack_kernel(
    const float* __restrict__ w2, const float* __restrict__ b2, u16* __restrict__ Bp)
{
  int gid = blockIdx.x * 256 + threadIdx.x;
  if (gid >= NKT * 128) return;
  int lane = gid & 63;
  int nt = (gid >> 6) & 1;
  int kt = gid >> 7;
  int o = nt * 32 + (lane & 31);
  int kbase = kt * 16 + (lane >> 5) * 8;
  u16 vals[8];
  #pragma unroll
  for (int j = 0; j < 8; ++j) {
    int k = kbase + j;
    vals[j] = f2bf((k < 4096) ? w2[(k >> 6) * 4096 + (k & 63) * 64 + o]
                              : b2[(k - 4096) * 64 + o]);
  }
  uint4 pack;
  pack.x = (unsigned)vals[0] | ((unsigned)vals[1] << 16);
  pack.y = (unsigned)vals[2] | ((unsigned)vals[3] << 16);
  pack.z = (unsigned)vals[4] | ((unsigned)vals[5] << 16);
  pack.w = (unsigned)vals[6] | ((unsigned)vals[7] << 16);
  *(uint4*)(Bp + (size_t)gid * 8) = pack;
}

// ---------------- bucketed CSR: one pass, no scan ----------------
__global__ __launch_bounds__(256) void hist_kernel(
    const int* __restrict__ eidx, int* __restrict__ cnt, int* __restrict__ elist, int E)
{
  int e = blockIdx.x * 256 + threadIdx.x;
  if (e < E) {
    int tg = eidx[E + e];
    int pos = atomicAdd(cnt + tg, 1);
    if (pos < DEG_CAP) elist[(size_t)tg * DEG_CAP + pos] = e;
  }
}

// ---------------- msg = [h (x) x, x] @ B_ext — single-wave block, zero barriers ----------------
// block = 64 thr = 1 wave = 64 edges (2 row tiles), full K, all 64 cols (4 accs).
// B streams from L2 via a depth-4 register ring (prefetch kt+4 each kt — fine-grained
// vmcnt, no __syncthreads anywhere). x in registers; h in a 2-deep uint4 ring with
// static extraction (blk/j/tt loop nest keeps all register indices compile-time).
__global__ __launch_bounds__(64) void msg_gemm_kernel(
    const u16* __restrict__ X, const u16* __restrict__ Hh,
    const u16* __restrict__ Bp, const int* __restrict__ eidx,
    float* __restrict__ msg, int E)
{
  const int lane = threadIdx.x;
  const int ml = lane & 31;
  const int q  = lane >> 5;
  const int e0 = blockIdx.x * 64;

  const int ea = e0 + ml, eb = e0 + 32 + ml;
  const int eac = ea < E ? ea : E - 1;
  const int ebc = eb < E ? eb : E - 1;
  const int sa = eidx[eac], sb = eidx[ebc];

  // x slices: xr?[s] covers elems [s*16 + q*8, +8) of the row
  U8 xra[4], xrb[4];
  {
    const u16* xpa = X + (size_t)sa * 64 + q * 8;
    const u16* xpb = X + (size_t)sb * 64 + q * 8;
    #pragma unroll
    for (int s = 0; s < 4; ++s) {
      xra[s].v = *(const uint4*)(xpa + s * 16);
      xrb[s].v = *(const uint4*)(xpb + s * 16);
    }
  }

  // h rows (8 uint4 each = 64 bf16), cur/next ring
  const uint4* ha4 = (const uint4*)(Hh + (size_t)eac * 64);
  const uint4* hb4 = (const uint4*)(Hh + (size_t)ebc * 64);
  uint4 hc0 = ha4[0], hn0 = ha4[1];
  uint4 hc1 = hb4[0], hn1 = hb4[1];

  // B register ring, depth 4 kt (8 uint4 in flight)
  const uint4* bpv = (const uint4*)Bp;
  uint4 rb0[4], rb1[4];
  #pragma unroll
  for (int p = 0; p < 4; ++p) {
    rb0[p] = bpv[p * 128 + lane];
    rb1[p] = bpv[p * 128 + 64 + lane];
  }

  float16_t acc00, acc01, acc10, acc11;
  #pragma unroll
  for (int i = 0; i < 16; ++i) { acc00[i] = 0.f; acc01[i] = 0.f; acc10[i] = 0.f; acc11[i] = 0.f; }

  for (int blk = 0; blk < 8; ++blk) {       // kq blocks of 8 (kq = 8*blk + j)
    #pragma unroll
    for (int j = 0; j < 8; ++j) {
      unsigned w0 = ((const unsigned*)&hc0)[j >> 1];
      unsigned w1 = ((const unsigned*)&hc1)[j >> 1];
      float hs0 = bf2f((u16)((j & 1) ? (w0 >> 16) : (w0 & 0xffffu)));
      float hs1 = bf2f((u16)((j & 1) ? (w1 >> 16) : (w1 & 0xffffu)));
      #pragma unroll
      for (int tt = 0; tt < 4; ++tt) {      // kt = kq*4 + tt; ring slot = tt
        int kt = ((blk * 8 + j) << 2) + tt;
        U8 b0, b1;
        b0.v = rb0[tt]; b1.v = rb1[tt];
        rb0[tt] = bpv[(kt + 4) * 128 + lane];        // kt+4 <= 259: always valid
        rb1[tt] = bpv[(kt + 4) * 128 + 64 + lane];
        short8_t a0 = scale8(xra[tt].s, hs0);
        short8_t a1 = scale8(xrb[tt].s, hs1);
        acc00 = __builtin_amdgcn_mfma_f32_32x32x16_bf16(a0, b0.s, acc00, 0, 0, 0);
        acc01 = __builtin_amdgcn_mfma_f32_32x32x16_bf16(a0, b1.s, acc01, 0, 0, 0);
        acc10 = __builtin_amdgcn_mfma_f32_32x32x16_bf16(a1, b0.s, acc10, 0, 0, 0);
        acc11 = __builtin_amdgcn_mfma_f32_32x32x16_bf16(a1, b1.s, acc11, 0, 0, 0);
      }
    }
    hc0 = hn0; hc1 = hn1;
    if (blk < 6) { hn0 = ha4[blk + 2]; hn1 = hb4[blk + 2]; }
  }
  // tail kt 256..259 (b2 rows): A = x exactly; ring slots hold kt 256..259
  #pragma unroll
  for (int tt = 0; tt < 4; ++tt) {
    U8 b0, b1;
    b0.v = rb0[tt]; b1.v = rb1[tt];
    acc00 = __builtin_amdgcn_mfma_f32_32x32x16_bf16(xra[tt].s, b0.s, acc00, 0, 0, 0);
    acc01 = __builtin_amdgcn_mfma_f32_32x32x16_bf16(xra[tt].s, b1.s, acc01, 0, 0, 0);
    acc10 = __builtin_amdgcn_mfma_f32_32x32x16_bf16(xrb[tt].s, b0.s, acc10, 0, 0, 0);
    acc11 = __builtin_amdgcn_mfma_f32_32x32x16_bf16(xrb[tt].s, b1.s, acc11, 0, 0, 0);
  }

  // epilogue: C/D layout col=lane&31, row=(reg&3)+8*(reg>>2)+4*q
  #pragma unroll
  for (int reg = 0; reg < 16; ++reg) {
    int row = (reg & 3) + 8 * (reg >> 2) + 4 * q;
    int e1 = e0 + row, e2 = e0 + 32 + row;
    if (e1 < E) {
      msg[(size_t)e1 * 64 + ml]      = acc00[reg];
      msg[(size_t)e1 * 64 + 32 + ml] = acc01[reg];
    }
    if (e2 < E) {
      msg[(size_t)e2 * 64 + ml]      = acc10[reg];
      msg[(size_t)e2 * 64 + 32 + ml] = acc11[reg];
    }
  }
}

// ---------------- x_new = relu(x @ root + gather_mean(msg) + bias) ----------------
__global__ __launch_bounds__(256) void update_kernel(
    const u16* __restrict__ Xin, const float* __restrict__ msg,
    const int* __restrict__ cnt, const int* __restrict__ elist,
    const float* __restrict__ root, const float* __restrict__ bias,
    u16* __restrict__ Xout, int N)
{
  __shared__ float root_s[64 * 64];
  int t = threadIdx.x;
  for (int idx = t; idx < 4096; idx += 256) root_s[idx] = root[idx];
  __syncthreads();
  int o = t & 63, ln = t >> 6;
  int n0 = blockIdx.x * 16 + ln * 4;
  for (int s = 0; s < 4; ++s) {
    int n = n0 + s;
    if (n >= N) break;                       // wave-uniform
    int c = cnt[n];
    int cc = c < DEG_CAP ? c : DEG_CAP;
    float agg = 0.f;
    for (int j = 0; j < cc; ++j) {
      int e = elist[(size_t)n * DEG_CAP + j];
      agg += msg[(size_t)e * 64 + o];
    }
    if (c > 1) agg *= 1.0f / (float)c;
    float xv = bf2f(Xin[(size_t)n * 64 + o]);
    float acc = bias[o] + agg;
    #pragma unroll
    for (int i = 0; i < 64; ++i)
      acc = fmaf(__shfl(xv, i, 64), root_s[i * 64 + o], acc);
    Xout[(size_t)n * 64 + o] = f2bf(fmaxf(acc, 0.f));
  }
}

// ---------------- column-sum pool: vectorized grid-stride ----------------
__global__ __launch_bounds__(256) void pool_kernel(const u16* __restrict__ X, float* __restrict__ out64, int nchunks)
{
  __shared__ float red[64];
  int t = threadIdx.x;
  if (t < 64) red[t] = 0.f;
  __syncthreads();
  int gid = blockIdx.x * 256 + t;
  float s[8];
  #pragma unroll
  for (int j = 0; j < 8; ++j) s[j] = 0.f;
  for (int i = gid; i < nchunks; i += 256 * 256) {
    uint4 v = ((const uint4*)X)[i];
    s[0] += bf2f((u16)(v.x & 0xffffu)); s[1] += bf2f((u16)(v.x >> 16));
    s[2] += bf2f((u16)(v.y & 0xffffu)); s[3] += bf2f((u16)(v.y >> 16));
    s[4] += bf2f((u16)(v.z & 0xffffu)); s[5] += bf2f((u16)(v.z >> 16));
    s[6] += bf2f((u16)(v.w & 0xffffu)); s[7] += bf2f((u16)(v.w >> 16));
  }
  int cg = (gid & 7) * 8;
  #pragma unroll
  for (int j = 0; j < 8; ++j) atomicAdd(red + cg + j, s[j]);
  __syncthreads();
  if (t < 64) atomicAdd(out64 + t, red[t]);
}

// ---------------- head: parallel per-layer GEMV ----------------
__global__ __launch_bounds__(256) void prep_head_kernel(
    const float* __restrict__ pg, const float* __restrict__ plg, const float* __restrict__ adduct,
    float* __restrict__ v)
{
  int t = threadIdx.x;
  if (t < 131) v[t] = (t < 64) ? pg[t] : (t < 128 ? plg[t - 64] : adduct[t - 128]);
}

__global__ __launch_bounds__(256) void gemv_relu_kernel(
    const float* __restrict__ in, const float* __restrict__ W, const float* __restrict__ b,
    float* __restrict__ out, int Ni, int No)
{
  __shared__ float red[16][17];
  int t = threadIdx.x;
  int ol = t & 15, ig = t >> 4;
  int o = blockIdx.x * 16 + ol;
  float s = 0.f;
  for (int i = ig; i < Ni; i += 16)
    s = fmaf(in[i], W[i * No + o], s);
  red[ig][ol] = s;
  __syncthreads();
  if (t < 16) {
    int oo = blockIdx.x * 16 + t;
    float acc = b[oo];
    #pragma unroll
    for (int g = 0; g < 16; ++g) acc += red[g][t];
    out[oo] = fmaxf(acc, 0.f);
  }
}

__global__ __launch_bounds__(384) void final_kernel(
    const float* __restrict__ u, const float* __restrict__ l2w, const float* __restrict__ l2b,
    float* __restrict__ out)
{
  __shared__ float wred[6];
  int t = threadIdx.x;
  float p = u[t] * l2w[t];
  #pragma unroll
  for (int off = 32; off > 0; off >>= 1) p += __shfl_down(p, off);
  if ((t & 63) == 0) wred[t >> 6] = p;
  __syncthreads();
  if (t == 0) {
    float s = l2b[0];
    #pragma unroll
    for (int i = 0; i < 6; ++i) s += wred[i];
    out[0] = s;
  }
}

// ---------------- host driver ----------------
template<int INX, int INE>
static void run_branch(const float* Xraw, const float* l0w, const float* l0b,
                       const int* eidx, const float* ea,
                       const float* w1, const float* b1, const float* w2, const float* b2,
                       const float* root, const float* bias,
                       int N, int E,
                       u16* xa, u16* xb, u16* hbuf, u16* bp,
                       float* msg, int* cnt, int* elist, float* pool,
                       hipStream_t stream)
{
  affine_relu_kernel<INX><<<(N * 64 + 255) / 256, 256, 0, stream>>>(Xraw, l0w, l0b, xa, N);
  affine_relu_kernel<INE><<<(E * 64 + 255) / 256, 256, 0, stream>>>(ea, w1, b1, hbuf, E);
  bpack_kernel<<<(NKT * 128 + 255) / 256, 256, 0, stream>>>(w2, b2, bp);
  hipMemsetAsync(cnt, 0, (size_t)N * 4, stream);
  hist_kernel<<<(E + 255) / 256, 256, 0, stream>>>(eidx, cnt, elist, E);
  u16* xc = xa; u16* xn = xb;
  for (int it = 0; it < 3; ++it) {
    msg_gemm_kernel<<<(E + 63) / 64, 64, 0, stream>>>(xc, hbuf, bp, eidx, msg, E);
    update_kernel<<<(N + 15) / 16, 256, 0, stream>>>(xc, msg, cnt, elist, root, bias, xn, N);
    u16* tmp = xc; xc = xn; xn = tmp;
  }
  hipMemsetAsync(pool, 0, 64 * 4, stream);
  pool_kernel<<<256, 256, 0, stream>>>(xc, pool, N * 8);
}

extern "C" void kernel_launch(void* const* d_in, const int* in_sizes, int n_in,
                              void* d_out, int out_size, void* d_ws, size_t ws_size,
                              hipStream_t stream)
{
  const int NG = 30000, EG = 60000, NLG = 60000, ELG = 60000;

  const float* gx      = (const float*)d_in[0];
  const int*   g_ei    = (const int*)  d_in[1];
  const float* g_ea    = (const float*)d_in[2];
  const float* lgx     = (const float*)d_in[3];
  const int*   lg_ei   = (const int*)  d_in[4];
  const float* lg_ea   = (const float*)d_in[5];
  const float* adduct  = (const float*)d_in[6];
  const float* lin0_w  = (const float*)d_in[7];
  const float* lin0_b  = (const float*)d_in[8];
  const float* g_w1    = (const float*)d_in[9];
  const float* g_b1    = (const float*)d_in[10];
  const float* g_w2    = (const float*)d_in[11];
  const float* g_b2    = (const float*)d_in[12];
  const float* g_root  = (const float*)d_in[13];
  const float* g_bias  = (const float*)d_in[14];
  const float* l0lg_w  = (const float*)d_in[15];
  const float* l0lg_b  = (const float*)d_in[16];
  const float* lg_w1   = (const float*)d_in[17];
  const float* lg_b1   = (const float*)d_in[18];
  const float* lg_w2   = (const float*)d_in[19];
  const float* lg_b2   = (const float*)d_in[20];
  const float* lg_root = (const float*)d_in[21];
  const float* lg_bias = (const float*)d_in[22];
  const float* bott_w  = (const float*)d_in[23];
  const float* bott_b  = (const float*)d_in[24];
  const float* lin1_w  = (const float*)d_in[25];
  const float* lin1_b  = (const float*)d_in[26];
  const float* lin2_w  = (const float*)d_in[27];
  const float* lin2_b  = (const float*)d_in[28];

  char* p = (char*)d_ws;
  auto alloc = [&](size_t bytes) { char* r = p; p += (bytes + 255) & ~(size_t)255; return r; };
  // shared between the two sequential branches (~47 MB total)
  u16*   xa     = (u16*)  alloc((size_t)NLG * 64 * 2);
  u16*   xb     = (u16*)  alloc((size_t)NLG * 64 * 2);
  u16*   hbuf   = (u16*)  alloc((size_t)ELG * 64 * 2);
  u16*   bp     = (u16*)  alloc((size_t)NKT * 128 * 8 * 2 + 4096);
  float* msg    = (float*)alloc((size_t)ELG * 64 * 4);
  int*   cnt    = (int*)  alloc((size_t)NLG * 4);
  int*   elist  = (int*)  alloc((size_t)NLG * DEG_CAP * 4);
  float* pool_g = (float*)alloc(64 * 4);
  float* pool_l = (float*)alloc(64 * 4);
  float* hv     = (float*)alloc(131 * 4);
  float* h0     = (float*)alloc(384 * 4);
  float* h1     = (float*)alloc(384 * 4);

  run_branch<20, 4>(gx, lin0_w, lin0_b, g_ei, g_ea, g_w1, g_b1, g_w2, g_b2, g_root, g_bias,
                    NG, EG, xa, xb, hbuf, bp, msg, cnt, elist, pool_g, stream);
  run_branch<5, 1>(lgx, l0lg_w, l0lg_b, lg_ei, lg_ea, lg_w1, lg_b1, lg_w2, lg_b2, lg_root, lg_bias,
                   NLG, ELG, xa, xb, hbuf, bp, msg, cnt, elist, pool_l, stream);

  prep_head_kernel<<<1, 256, 0, stream>>>(pool_g, pool_l, adduct, hv);
  gemv_relu_kernel<<<24, 256, 0, stream>>>(hv, bott_w, bott_b, h0, 131, 384);
  float* ua = h0; float* ub = h1;
  for (int L = 0; L < 6; ++L) {
    gemv_relu_kernel<<<24, 256, 0, stream>>>(ua, lin1_w, lin1_b, ub, 384, 384);
    float* tmp = ua; ua = ub; ub = tmp;
  }
  final_kernel<<<1, 384, 0, stream>>>(ua, lin2_w, lin2_b, (float*)d_out);
}

// Round 10
// 592.286 us; speedup vs baseline: 2.1664x; 1.5995x over previous
//
#include <hip/hip_runtime.h>

typedef unsigned short u16;
using short8_t  = __attribute__((ext_vector_type(8)))  short;
using float16_t = __attribute__((ext_vector_type(16))) float;

#define NKT 260          // K-steps of 16: K = 64*64 + 64 = 4160
#define DEG_CAP 32

__device__ __forceinline__ float bf2f(u16 b) { return __uint_as_float(((unsigned)b) << 16); }
__device__ __forceinline__ u16 f2bf(float f) {
  unsigned u = __float_as_uint(f);
  return (u16)((u + 0x7fffu + ((u >> 16) & 1u)) >> 16);   // RNE
}

union U8 { short8_t s; uint4 v; unsigned u[4]; };

// z = (h * x) rounded to bf16 (round-half-up), 8 elems; hs==1.0 reproduces x exactly
__device__ __forceinline__ short8_t scale8(short8_t x8, float hs) {
  U8 in, out;
  in.s = x8;
  #pragma unroll
  for (int p = 0; p < 4; ++p) {
    unsigned w = in.u[p];
    float lo = __uint_as_float(w << 16) * hs;
    float hi = __uint_as_float(w & 0xffff0000u) * hs;
    unsigned lor = __float_as_uint(lo) + 0x8000u;
    unsigned hir = __float_as_uint(hi) + 0x8000u;
    out.u[p] = __builtin_amdgcn_perm(hir, lor, 0x07060302);  // [hir.hi16 | lor.hi16]
  }
  return out.s;
}

// ---------------- relu(X @ W + b): f32 in, bf16 out. W is [IN,64] f32 ----------------
template<int IN>
__global__ __launch_bounds__(256) void affine_relu_kernel(
    const float* __restrict__ Xin, const float* __restrict__ W, const float* __restrict__ Bv,
    u16* __restrict__ Xout, int N)
{
  int gid = blockIdx.x * 256 + threadIdx.x;
  int n = gid >> 6, o = gid & 63;
  if (n >= N) return;
  float acc = Bv[o];
  #pragma unroll
  for (int i = 0; i < IN; ++i)
    acc = fmaf(Xin[n * IN + i], W[i * 64 + o], acc);
  Xout[gid] = f2bf(fmaxf(acc, 0.f));
}

// ---------------- pack B_ext [4160,64] (f32 w2/b2) into bf16 MFMA per-lane fragment order ----
__global__ __launch_bounds__(256) void bpack_kernel(
    const float* __restrict__ w2, const float* __restrict__ b2, u16* __restrict__ Bp)
{
  int gid = blockIdx.x * 256 + threadIdx.x;
  if (gid >= NKT * 128) return;
  int lane = gid & 63;
  int nt = (gid >> 6) & 1;
  int kt = gid >> 7;
  int o = nt * 32 + (lane & 31);
  int kbase = kt * 16 + (lane >> 5) * 8;
  u16 vals[8];
  #pragma unroll
  for (int j = 0; j < 8; ++j) {
    int k = kbase + j;
    vals[j] = f2bf((k < 4096) ? w2[(k >> 6) * 4096 + (k & 63) * 64 + o]
                              : b2[(k - 4096) * 64 + o]);
  }
  uint4 pack;
  pack.x = (unsigned)vals[0] | ((unsigned)vals[1] << 16);
  pack.y = (unsigned)vals[2] | ((unsigned)vals[3] << 16);
  pack.z = (unsigned)vals[4] | ((unsigned)vals[5] << 16);
  pack.w = (unsigned)vals[6] | ((unsigned)vals[7] << 16);
  *(uint4*)(Bp + (size_t)gid * 8) = pack;
}

// ---------------- pack root [64,64] f32 into bf16 fragment order (8 frags) ----------------
__global__ __launch_bounds__(256) void rootpack_kernel(const float* __restrict__ root, u16* __restrict__ Rp)
{
  int gid = blockIdx.x * 256 + threadIdx.x;   // 512 entries = (kt*2+nt)*64 + lane
  if (gid >= 512) return;
  int lane = gid & 63;
  int nt = (gid >> 6) & 1;
  int kt = gid >> 7;
  int o = nt * 32 + (lane & 31);
  int kbase = kt * 16 + (lane >> 5) * 8;
  u16 vals[8];
  #pragma unroll
  for (int j = 0; j < 8; ++j) vals[j] = f2bf(root[(kbase + j) * 64 + o]);
  uint4 pack;
  pack.x = (unsigned)vals[0] | ((unsigned)vals[1] << 16);
  pack.y = (unsigned)vals[2] | ((unsigned)vals[3] << 16);
  pack.z = (unsigned)vals[4] | ((unsigned)vals[5] << 16);
  pack.w = (unsigned)vals[6] | ((unsigned)vals[7] << 16);
  *(uint4*)(Rp + (size_t)gid * 8) = pack;
}

// ---------------- bucketed CSR: one pass, no scan ----------------
__global__ __launch_bounds__(256) void hist_kernel(
    const int* __restrict__ eidx, int* __restrict__ cnt, int* __restrict__ elist, int E)
{
  int e = blockIdx.x * 256 + threadIdx.x;
  if (e < E) {
    int tg = eidx[E + e];
    int pos = atomicAdd(cnt + tg, 1);
    if (pos < DEG_CAP) elist[(size_t)tg * DEG_CAP + pos] = e;
  }
}

// ---------------- msg = [h (x) x, x] @ B_ext — fused both branches, no barriers ----------------
// block = 256 thr = 4 independent waves; wave = 32 edges (M=32), full K, 64 cols.
// blockIdx < nbg -> branch g, else branch lg. B streams from L1/L2 via depth-4
// register ring (4 waves/block share the stream through L1). No LDS, no syncthreads.
__global__ __launch_bounds__(256, 4) void msg_gemm_kernel(
    const u16* __restrict__ Xg, const u16* __restrict__ Hg, const u16* __restrict__ Bg,
    const int* __restrict__ eig, float* __restrict__ Mg, int Eg, int nbg,
    const u16* __restrict__ Xl, const u16* __restrict__ Hl, const u16* __restrict__ Bl,
    const int* __restrict__ eil, float* __restrict__ Ml, int El)
{
  const int b = blockIdx.x;
  const u16 *X, *Hh, *Bp; const int* eidx; float* msg; int E, e0;
  if (b < nbg) { X = Xg; Hh = Hg; Bp = Bg; eidx = eig; msg = Mg; E = Eg; e0 = b * 128; }
  else         { X = Xl; Hh = Hl; Bp = Bl; eidx = eil; msg = Ml; E = El; e0 = (b - nbg) * 128; }

  const int t = threadIdx.x;
  const int lane = t & 63;
  const int wid = t >> 6;
  const int ml = lane & 31;
  const int q  = lane >> 5;

  const int ea = e0 + wid * 32 + ml;
  const int eac = ea < E ? ea : E - 1;
  const int sa = eidx[eac];

  // x slices: xra[s] covers elems [s*16 + q*8, +8) of the row
  U8 xra[4];
  {
    const u16* xpa = X + (size_t)sa * 64 + q * 8;
    #pragma unroll
    for (int s = 0; s < 4; ++s) xra[s].v = *(const uint4*)(xpa + s * 16);
  }

  // h row (8 uint4 = 64 bf16), cur/next ring
  const uint4* ha4 = (const uint4*)(Hh + (size_t)eac * 64);
  uint4 hc0 = ha4[0], hn0 = ha4[1];

  // B register ring, depth 4 kt (8 uint4 in flight)
  const uint4* bpv = (const uint4*)Bp;
  uint4 rb0[4], rb1[4];
  #pragma unroll
  for (int p = 0; p < 4; ++p) {
    rb0[p] = bpv[p * 128 + lane];
    rb1[p] = bpv[p * 128 + 64 + lane];
  }

  float16_t acc0, acc1;
  #pragma unroll
  for (int i = 0; i < 16; ++i) { acc0[i] = 0.f; acc1[i] = 0.f; }

  for (int blk = 0; blk < 8; ++blk) {       // kq = 8*blk + j
    #pragma unroll
    for (int j = 0; j < 8; ++j) {
      unsigned w0 = ((const unsigned*)&hc0)[j >> 1];
      float hs0 = bf2f((u16)((j & 1) ? (w0 >> 16) : (w0 & 0xffffu)));
      #pragma unroll
      for (int tt = 0; tt < 4; ++tt) {      // kt = kq*4 + tt
        int kt = ((blk * 8 + j) << 2) + tt;
        U8 b0, b1;
        b0.v = rb0[tt]; b1.v = rb1[tt];
        rb0[tt] = bpv[(kt + 4) * 128 + lane];        // kt+4 <= 259
        rb1[tt] = bpv[(kt + 4) * 128 + 64 + lane];
        short8_t a0 = scale8(xra[tt].s, hs0);
        acc0 = __builtin_amdgcn_mfma_f32_32x32x16_bf16(a0, b0.s, acc0, 0, 0, 0);
        acc1 = __builtin_amdgcn_mfma_f32_32x32x16_bf16(a0, b1.s, acc1, 0, 0, 0);
      }
    }
    hc0 = hn0;
    if (blk < 6) hn0 = ha4[blk + 2];
  }
  // tail kt 256..259 (b2 rows): A = x exactly
  #pragma unroll
  for (int tt = 0; tt < 4; ++tt) {
    U8 b0, b1;
    b0.v = rb0[tt]; b1.v = rb1[tt];
    acc0 = __builtin_amdgcn_mfma_f32_32x32x16_bf16(xra[tt].s, b0.s, acc0, 0, 0, 0);
    acc1 = __builtin_amdgcn_mfma_f32_32x32x16_bf16(xra[tt].s, b1.s, acc1, 0, 0, 0);
  }

  // epilogue: C/D layout col=lane&31, row=(reg&3)+8*(reg>>2)+4*q
  #pragma unroll
  for (int reg = 0; reg < 16; ++reg) {
    int row = (reg & 3) + 8 * (reg >> 2) + 4 * q;
    int e1 = e0 + wid * 32 + row;
    if (e1 < E) {
      msg[(size_t)e1 * 64 + ml]      = acc0[reg];
      msg[(size_t)e1 * 64 + 32 + ml] = acc1[reg];
    }
  }
}

// ---------------- x_new = relu(x @ root + gather_mean(msg) + bias) — MFMA, fused ----------------
// block 256 = 4 waves x 32 nodes = 128 nodes; root pre-packed (8 frags in regs).
__global__ __launch_bounds__(256, 4) void update_kernel(
    const u16* __restrict__ Xig, const float* __restrict__ Mgg, const int* __restrict__ cg,
    const int* __restrict__ elg, const u16* __restrict__ rpg, const float* __restrict__ bg,
    u16* __restrict__ Xog, int Ng, int nbg,
    const u16* __restrict__ Xil, const float* __restrict__ Mgl, const int* __restrict__ cl,
    const int* __restrict__ ell, const u16* __restrict__ rpl, const float* __restrict__ bl,
    u16* __restrict__ Xol, int Nl)
{
  const int b = blockIdx.x;
  const u16 *Xin, *rootp; const float *msg, *bias; const int *cnt, *elist;
  u16* Xout; int N, n0;
  if (b < nbg) { Xin=Xig; msg=Mgg; cnt=cg; elist=elg; rootp=rpg; bias=bg; Xout=Xog; N=Ng; n0=b*128; }
  else         { Xin=Xil; msg=Mgl; cnt=cl; elist=ell; rootp=rpl; bias=bl; Xout=Xol; N=Nl; n0=(b-nbg)*128; }

  const int t = threadIdx.x;
  const int lane = t & 63;
  const int wid = t >> 6;
  const int ml = lane & 31;
  const int q  = lane >> 5;
  const int nbase = n0 + wid * 32;

  const int na = nbase + ml;
  const int nac = na < N ? na : N - 1;

  U8 xr[4];
  {
    const u16* xp = Xin + (size_t)nac * 64 + q * 8;
    #pragma unroll
    for (int s = 0; s < 4; ++s) xr[s].v = *(const uint4*)(xp + s * 16);
  }
  U8 rp[8];
  {
    const uint4* rpv = (const uint4*)rootp;
    #pragma unroll
    for (int i = 0; i < 8; ++i) rp[i].v = rpv[i * 64 + lane];
  }
  const float bias0 = bias[ml], bias1 = bias[32 + ml];

  float16_t acc0, acc1;
  #pragma unroll
  for (int i = 0; i < 16; ++i) { acc0[i] = 0.f; acc1[i] = 0.f; }
  #pragma unroll
  for (int kt = 0; kt < 4; ++kt) {
    acc0 = __builtin_amdgcn_mfma_f32_32x32x16_bf16(xr[kt].s, rp[kt * 2 + 0].s, acc0, 0, 0, 0);
    acc1 = __builtin_amdgcn_mfma_f32_32x32x16_bf16(xr[kt].s, rp[kt * 2 + 1].s, acc1, 0, 0, 0);
  }

  #pragma unroll
  for (int reg = 0; reg < 16; ++reg) {
    int row = (reg & 3) + 8 * (reg >> 2) + 4 * q;
    int nn = nbase + row;
    if (nn < N) {
      int c = cnt[nn];
      int cc = c < DEG_CAP ? c : DEG_CAP;
      float a0 = 0.f, a1 = 0.f;
      for (int j = 0; j < cc; ++j) {
        int e = elist[(size_t)nn * DEG_CAP + j];
        a0 += msg[(size_t)e * 64 + ml];
        a1 += msg[(size_t)e * 64 + 32 + ml];
      }
      float rc = (c > 1) ? (1.0f / (float)c) : 1.0f;
      float o0 = fmaxf(acc0[reg] + a0 * rc + bias0, 0.f);
      float o1 = fmaxf(acc1[reg] + a1 * rc + bias1, 0.f);
      Xout[(size_t)nn * 64 + ml]      = f2bf(o0);
      Xout[(size_t)nn * 64 + 32 + ml] = f2bf(o1);
    }
  }
}

// ---------------- column-sum pool: vectorized grid-stride ----------------
__global__ __launch_bounds__(256) void pool_kernel(const u16* __restrict__ X, float* __restrict__ out64, int nchunks)
{
  __shared__ float red[64];
  int t = threadIdx.x;
  if (t < 64) red[t] = 0.f;
  __syncthreads();
  int gid = blockIdx.x * 256 + t;
  float s[8];
  #pragma unroll
  for (int j = 0; j < 8; ++j) s[j] = 0.f;
  for (int i = gid; i < nchunks; i += 256 * 256) {
    uint4 v = ((const uint4*)X)[i];
    s[0] += bf2f((u16)(v.x & 0xffffu)); s[1] += bf2f((u16)(v.x >> 16));
    s[2] += bf2f((u16)(v.y & 0xffffu)); s[3] += bf2f((u16)(v.y >> 16));
    s[4] += bf2f((u16)(v.z & 0xffffu)); s[5] += bf2f((u16)(v.z >> 16));
    s[6] += bf2f((u16)(v.w & 0xffffu)); s[7] += bf2f((u16)(v.w >> 16));
  }
  int cg = (gid & 7) * 8;
  #pragma unroll
  for (int j = 0; j < 8; ++j) atomicAdd(red + cg + j, s[j]);
  __syncthreads();
  if (t < 64) atomicAdd(out64 + t, red[t]);
}

// ---------------- head: parallel per-layer GEMV ----------------
__global__ __launch_bounds__(256) void prep_head_kernel(
    const float* __restrict__ pg, const float* __restrict__ plg, const float* __restrict__ adduct,
    float* __restrict__ v)
{
  int t = threadIdx.x;
  if (t < 131) v[t] = (t < 64) ? pg[t] : (t < 128 ? plg[t - 64] : adduct[t - 128]);
}

__global__ __launch_bounds__(256) void gemv_relu_kernel(
    const float* __restrict__ in, const float* __restrict__ W, const float* __restrict__ b,
    float* __restrict__ out, int Ni, int No)
{
  __shared__ float red[16][17];
  int t = threadIdx.x;
  int ol = t & 15, ig = t >> 4;
  int o = blockIdx.x * 16 + ol;
  float s = 0.f;
  for (int i = ig; i < Ni; i += 16)
    s = fmaf(in[i], W[i * No + o], s);
  red[ig][ol] = s;
  __syncthreads();
  if (t < 16) {
    int oo = blockIdx.x * 16 + t;
    float acc = b[oo];
    #pragma unroll
    for (int g = 0; g < 16; ++g) acc += red[g][t];
    out[oo] = fmaxf(acc, 0.f);
  }
}

__global__ __launch_bounds__(384) void final_kernel(
    const float* __restrict__ u, const float* __restrict__ l2w, const float* __restrict__ l2b,
    float* __restrict__ out)
{
  __shared__ float wred[6];
  int t = threadIdx.x;
  float p = u[t] * l2w[t];
  #pragma unroll
  for (int off = 32; off > 0; off >>= 1) p += __shfl_down(p, off);
  if ((t & 63) == 0) wred[t >> 6] = p;
  __syncthreads();
  if (t == 0) {
    float s = l2b[0];
    #pragma unroll
    for (int i = 0; i < 6; ++i) s += wred[i];
    out[0] = s;
  }
}

extern "C" void kernel_launch(void* const* d_in, const int* in_sizes, int n_in,
                              void* d_out, int out_size, void* d_ws, size_t ws_size,
                              hipStream_t stream)
{
  const int NG = 30000, EG = 60000, NLG = 60000, ELG = 60000;

  const float* gx      = (const float*)d_in[0];
  const int*   g_ei    = (const int*)  d_in[1];
  const float* g_ea    = (const float*)d_in[2];
  const float* lgx     = (const float*)d_in[3];
  const int*   lg_ei   = (const int*)  d_in[4];
  const float* lg_ea   = (const float*)d_in[5];
  const float* adduct  = (const float*)d_in[6];
  const float* lin0_w  = (const float*)d_in[7];
  const float* lin0_b  = (const float*)d_in[8];
  const float* g_w1    = (const float*)d_in[9];
  const float* g_b1    = (const float*)d_in[10];
  const float* g_w2    = (const float*)d_in[11];
  const float* g_b2    = (const float*)d_in[12];
  const float* g_root  = (const float*)d_in[13];
  const float* g_bias  = (const float*)d_in[14];
  const float* l0lg_w  = (const float*)d_in[15];
  const float* l0lg_b  = (const float*)d_in[16];
  const float* lg_w1   = (const float*)d_in[17];
  const float* lg_b1   = (const float*)d_in[18];
  const float* lg_w2   = (const float*)d_in[19];
  const float* lg_b2   = (const float*)d_in[20];
  const float* lg_root = (const float*)d_in[21];
  const float* lg_bias = (const float*)d_in[22];
  const float* bott_w  = (const float*)d_in[23];
  const float* bott_b  = (const float*)d_in[24];
  const float* lin1_w  = (const float*)d_in[25];
  const float* lin1_b  = (const float*)d_in[26];
  const float* lin2_w  = (const float*)d_in[27];
  const float* lin2_b  = (const float*)d_in[28];

  char* p = (char*)d_ws;
  auto alloc = [&](size_t bytes) { char* r = p; p += (bytes + 255) & ~(size_t)255; return r; };
  // per-branch buffers (~83 MB total)
  u16*   xg_a   = (u16*)  alloc((size_t)NG  * 64 * 2);
  u16*   xg_b   = (u16*)  alloc((size_t)NG  * 64 * 2);
  u16*   xl_a   = (u16*)  alloc((size_t)NLG * 64 * 2);
  u16*   xl_b   = (u16*)  alloc((size_t)NLG * 64 * 2);
  u16*   h_g    = (u16*)  alloc((size_t)EG  * 64 * 2);
  u16*   h_l    = (u16*)  alloc((size_t)ELG * 64 * 2);
  u16*   bp_g   = (u16*)  alloc((size_t)NKT * 128 * 8 * 2 + 4096);
  u16*   bp_l   = (u16*)  alloc((size_t)NKT * 128 * 8 * 2 + 4096);
  u16*   rp_g   = (u16*)  alloc(512 * 8 * 2);
  u16*   rp_l   = (u16*)  alloc(512 * 8 * 2);
  float* msg_g  = (float*)alloc((size_t)EG  * 64 * 4);
  float* msg_l  = (float*)alloc((size_t)ELG * 64 * 4);
  int*   cnt_g  = (int*)  alloc((size_t)NG  * 4);
  int*   cnt_l  = (int*)  alloc((size_t)NLG * 4);
  int*   el_g   = (int*)  alloc((size_t)NG  * DEG_CAP * 4);
  int*   el_l   = (int*)  alloc((size_t)NLG * DEG_CAP * 4);
  float* pool_g = (float*)alloc(64 * 4);
  float* pool_l = (float*)alloc(64 * 4);
  float* hv     = (float*)alloc(131 * 4);
  float* h0     = (float*)alloc(384 * 4);
  float* h1     = (float*)alloc(384 * 4);

  // ---- setup both branches ----
  affine_relu_kernel<20><<<(NG * 64 + 255) / 256, 256, 0, stream>>>(gx, lin0_w, lin0_b, xg_a, NG);
  affine_relu_kernel<5><<<(NLG * 64 + 255) / 256, 256, 0, stream>>>(lgx, l0lg_w, l0lg_b, xl_a, NLG);
  affine_relu_kernel<4><<<(EG * 64 + 255) / 256, 256, 0, stream>>>(g_ea, g_w1, g_b1, h_g, EG);
  affine_relu_kernel<1><<<(ELG * 64 + 255) / 256, 256, 0, stream>>>(lg_ea, lg_w1, lg_b1, h_l, ELG);
  bpack_kernel<<<(NKT * 128 + 255) / 256, 256, 0, stream>>>(g_w2, g_b2, bp_g);
  bpack_kernel<<<(NKT * 128 + 255) / 256, 256, 0, stream>>>(lg_w2, lg_b2, bp_l);
  rootpack_kernel<<<2, 256, 0, stream>>>(g_root, rp_g);
  rootpack_kernel<<<2, 256, 0, stream>>>(lg_root, rp_l);
  hipMemsetAsync(cnt_g, 0, (size_t)NG * 4, stream);
  hipMemsetAsync(cnt_l, 0, (size_t)NLG * 4, stream);
  hist_kernel<<<(EG + 255) / 256, 256, 0, stream>>>(g_ei, cnt_g, el_g, EG);
  hist_kernel<<<(ELG + 255) / 256, 256, 0, stream>>>(lg_ei, cnt_l, el_l, ELG);

  // ---- fused 3-iteration loop ----
  const int nbg_m = (EG + 127) / 128, nbl_m = (ELG + 127) / 128;
  const int nbg_u = (NG + 127) / 128, nbl_u = (NLG + 127) / 128;
  u16 *xgc = xg_a, *xgn = xg_b, *xlc = xl_a, *xln = xl_b;
  for (int it = 0; it < 3; ++it) {
    msg_gemm_kernel<<<nbg_m + nbl_m, 256, 0, stream>>>(
        xgc, h_g, bp_g, g_ei, msg_g, EG, nbg_m,
        xlc, h_l, bp_l, lg_ei, msg_l, ELG);
    update_kernel<<<nbg_u + nbl_u, 256, 0, stream>>>(
        xgc, msg_g, cnt_g, el_g, rp_g, g_bias, xgn, NG, nbg_u,
        xlc, msg_l, cnt_l, el_l, rp_l, lg_bias, xln, NLG);
    u16* tmp = xgc; xgc = xgn; xgn = tmp;
    tmp = xlc; xlc = xln; xln = tmp;
  }

  hipMemsetAsync(pool_g, 0, 64 * 4, stream);
  hipMemsetAsync(pool_l, 0, 64 * 4, stream);
  pool_kernel<<<256, 256, 0, stream>>>(xgc, pool_g, NG * 8);
  pool_kernel<<<256, 256, 0, stream>>>(xlc, pool_l, NLG * 8);

  prep_head_kernel<<<1, 256, 0, stream>>>(pool_g, pool_l, adduct, hv);
  gemv_relu_kernel<<<24, 256, 0, stream>>>(hv, bott_w, bott_b, h0, 131, 384);
  float* ua = h0; float* ub = h1;
  for (int L = 0; L < 6; ++L) {
    gemv_relu_kernel<<<24, 256, 0, stream>>>(ua, lin1_w, lin1_b, ub, 384, 384);
    float* tmp = ua; ua = ub; ub = tmp;
  }
  final_kernel<<<1, 384, 0, stream>>>(ua, lin2_w, lin2_b, (float*)d_out);
}